// Round 1
// baseline (1683.719 us; speedup 1.0000x reference)
//
#include <hip/hip_runtime.h>

// Problem constants
#define T_STEPS 512
#define BATCH   256
#define DIN     128
#define DH      512
#define DOUT    128
#define RGRP    16         // rowgroups (BATCH/16), one block each

typedef __attribute__((ext_vector_type(8))) short  short8;   // 8 bf16 (4 VGPRs)
typedef __attribute__((ext_vector_type(4))) float  floatx4;  // MFMA acc
typedef __attribute__((ext_vector_type(4))) unsigned short ushort4v;

union Pack8 { short8 s; unsigned short h[8]; };

__device__ __forceinline__ float bf2f(unsigned short u) {
    union { unsigned int i; float f; } v; v.i = ((unsigned int)u) << 16; return v.f;
}
__device__ __forceinline__ unsigned short f2bf(float f) {
    union { float f; unsigned int i; } v; v.f = f;
    unsigned int b = v.i;
    b += 0x7FFFu + ((b >> 16) & 1u);   // RNE
    return (unsigned short)(b >> 16);
}
__device__ __forceinline__ float fast_tanh(float v) {
    float ex = __expf(v + v);
    return 1.f - 2.f / (ex + 1.f);
}

// ---------------------------------------------------------------------------
// Pack row-major fp32 [K][N] into bf16 B-fragment order:
//   Wp[ntile][kc][lane][8], lane = quad*16 + (n&15), j = k&7.
// ---------------------------------------------------------------------------
__global__ void pack_b_kernel(const float* __restrict__ W,
                              unsigned short* __restrict__ Wp, int K, int N) {
    int idx = blockIdx.x * blockDim.x + threadIdx.x;
    if (idx >= K * N) return;
    int k = idx / N, n = idx % N;
    int nt = n >> 4, kc = k >> 5, quad = (k >> 3) & 3, j = k & 7;
    int lane = quad * 16 + (n & 15);
    int KC = K >> 5;
    Wp[((size_t)(nt * KC + kc) * 64 + lane) * 8 + j] = f2bf(W[idx]);
}

// ---------------------------------------------------------------------------
// xproj: xpe holds (xs @ W1x + b1) in the rnn-epilogue consumption layout:
//   xpe[(t*16+rg)][cw 0..7][lane 0..63][ci 0..3][r 0..3]  (ushort each)
// so that rnn thread (w=cw, lane) reads its 16 addends as 2x b128.
// ---------------------------------------------------------------------------
__global__ __launch_bounds__(256) void xproj_kernel(
        const float* __restrict__ xs,
        const unsigned short* __restrict__ W1xp,
        const float* __restrict__ b1p,
        unsigned short* __restrict__ xpe) {
    const int tid  = threadIdx.x;
    const int lane = tid & 63;
    const int w    = tid >> 6;
    const int m    = lane & 15;
    const int q    = lane >> 4;
    const long row0 = (long)blockIdx.x * 16;
    const float b1 = b1p[0];

    short8 a[4];
#pragma unroll
    for (int kc = 0; kc < 4; ++kc) {
        const float* src = xs + (row0 + m) * DIN + kc * 32 + q * 8;
        Pack8 av;
#pragma unroll
        for (int j = 0; j < 8; ++j) av.h[j] = f2bf(src[j]);
        a[kc] = av.s;
    }

#pragma unroll
    for (int i = 0; i < 8; ++i) {
        const int nt = w * 8 + i;
        floatx4 acc = {0.f, 0.f, 0.f, 0.f};
#pragma unroll
        for (int kc = 0; kc < 4; ++kc) {
            short8 b = *(const short8*)(W1xp + ((size_t)(nt * 4 + kc) * 64 + lane) * 8);
            acc = __builtin_amdgcn_mfma_f32_16x16x32_bf16(a[kc], b, acc, 0, 0, 0);
        }
        ushort4v sv;
#pragma unroll
        for (int r = 0; r < 4; ++r) sv[r] = f2bf(acc[r] + b1);
        // value (row q*4+r, col nt*16+m) -> consumer (cw=nt>>2, lane, ci=nt&3, r)
        *(ushort4v*)&xpe[((size_t)blockIdx.x * 512 +
                          (size_t)(nt >> 2) * 64 + lane) * 16 + (nt & 3) * 4] = sv;
    }
}

// ---------------------------------------------------------------------------
// Recurrence: 16 blocks x 512 threads (8 waves, 2/SIMD, 256-VGPR budget pinned
// via amdgpu_waves_per_eu(2,2)). Wave w owns ntiles 4w..4w+3 (64 h-cols).
// W1h residency, balanced against the two memory pipes:
//   kc 0..9   -> registers (bfr: 160 VGPRs/lane, 320 KB/CU) - must stay live!
//   kc 10..11 -> LDS (Wl, 64 KB, written once)
//   kc 12..15 -> streamed from L2 every step (consume-then-prefetch pairs)
// Per-step pipe budget: LDS = 128KB(h-frags) + 64KB(Wl) ~= 2260 cyc;
//                       L2  = 128KB streamed          ~= 2000 cyc (overlapped)
// h kept in LDS in A-fragment layout (double-buffered, 2x16KB):
//   Hb[p][kc][slot][8], slot = lane' ^ ((lane'>>4)<<2) ^ (((lane'>>3)&1)<<1)
//   -> ds_read_b128 conflict-free; epilogue b16 writes 4-way (was 8-way).
// An asm memory clobber at the top of each step defeats LICM hoisting of the
// (loop-invariant-address) streamed-weight loads, which previously exploded
// register pressure and got bfr evicted to scratch (the old 7080 cyc/step).
// ---------------------------------------------------------------------------
template <int LKC>
__global__ __launch_bounds__(512) __attribute__((amdgpu_waves_per_eu(2, 2)))
void rnn_kernel(const unsigned short* __restrict__ xpe,
                const unsigned short* __restrict__ W1hp,
                const float* __restrict__ W2,
                const float* __restrict__ b2p,
                float* __restrict__ out) {
    extern __shared__ unsigned short smem[];
    unsigned short* Hb = smem;              // [2][16][64][8] ushort = 32768 B
    unsigned short* Wl = smem + 16384;      // [LKC][32][64][8]

    const int tid  = threadIdx.x;
    const int lane = tid & 63;
    const int w    = tid >> 6;      // 0..7
    const int m    = lane & 15;
    const int q    = lane >> 4;
    const int rg   = blockIdx.x;

    constexpr int RKC  = 10;            // register-resident kc count
    constexpr int SKC0 = RKC + LKC;     // first streamed kc
    constexpr int NS   = 16 - RKC - LKC;

    // ---- preload register-resident W1h (kc 0..RKC-1, wave's 4 ntiles) ----
    short8 bfr[RKC][4];
#pragma unroll
    for (int kc = 0; kc < RKC; ++kc)
#pragma unroll
        for (int i = 0; i < 4; ++i)
            bfr[kc][i] = *(const short8*)(W1hp +
                ((size_t)((4 * w + i) * 16 + kc) * 64 + lane) * 8);

    // ---- fill LDS-resident W1h (kc RKC..RKC+LKC-1) ----
    if (LKC > 0) {
        for (int c = tid; c < LKC * 2048; c += 512) {
            int j = c >> 11;          // kc-local
            int r2 = c & 2047;        // nt*64 + ln
            int nt = r2 >> 6, ln = r2 & 63;
            *(short8*)&Wl[(size_t)c * 8] =
                *(const short8*)(W1hp + ((size_t)(nt * 16 + RKC + j) * 64 + ln) * 8);
        }
    }

    // ---- addressing: A-frag slot swizzle (read side) ----
    const int slot = lane ^ ((lane >> 4) << 2) ^ (((lane >> 3) & 1) << 1);
    int roff = slot * 8;                 // ushort index into current read buf

    // write addresses: value (i, r) -> Hb[widx[i] ^ (r<<3)]
    int widx[4];
#pragma unroll
    for (int i = 0; i < 4; ++i) {
        int kcp = 2 * w + (i >> 1);
        int qp  = (2 * i + (m >> 3)) & 3;
        int lp  = 4 * q + 16 * qp;       // lane' at r=0
        int sl  = lp ^ ((lp >> 4) << 2) ^ (((lp >> 3) & 1) << 1);
        widx[i] = kcp * 512 + sl * 8 + (m & 7);
    }

    // ---- h^1 = tanh(xpe[0]) -> buf0 (b1 already folded into xpe) ----
    {
        const unsigned short* xb =
            xpe + ((size_t)rg * 512 + (size_t)w * 64 + lane) * 16;
        Pack8 x0, x1;
        x0.s = ((const short8*)xb)[0];
        x1.s = ((const short8*)xb)[1];
#pragma unroll
        for (int i = 0; i < 4; ++i) {
            Pack8 xh = (i < 2) ? x0 : x1;
#pragma unroll
            for (int r = 0; r < 4; ++r) {
                float v = bf2f(xh.h[(i & 1) * 4 + r]);
                Hb[widx[i] ^ (r << 3)] = f2bf(fast_tanh(v));
            }
            widx[i] ^= 8192;             // next write -> buf1
        }
    }
    __syncthreads();

#pragma unroll 1
    for (int t = 1; t < T_STEPS; ++t) {
        // Defeat LICM: addresses of the streamed loads below are
        // loop-invariant; without this they get hoisted, blow past the
        // 256-VGPR cap, and RA evicts bfr to scratch (measured r0 failure).
        asm volatile("" ::: "memory");

        const unsigned short* hrd = Hb + roff;

        // streamed-weight prefetch: groups 0,1 (kc SKC0, SKC0+1)
        short8 sb[2][4];
#pragma unroll
        for (int g = 0; g < 2; ++g)
#pragma unroll
            for (int i = 0; i < 4; ++i)
                sb[g][i] = *(const short8*)(W1hp +
                    ((size_t)((4 * w + i) * 16 + SKC0 + g) * 64 + lane) * 8);

        // xpe[t] prefetch (HBM latency hidden under the MFMA body)
        Pack8 x0, x1;
        {
            const unsigned short* xb = xpe +
                (((size_t)t * 16 + rg) * 512 + (size_t)w * 64 + lane) * 16;
            x0.s = ((const short8*)xb)[0];
            x1.s = ((const short8*)xb)[1];
        }

        floatx4 acc[4];
#pragma unroll
        for (int i = 0; i < 4; ++i) acc[i] = (floatx4){0.f, 0.f, 0.f, 0.f};

        // register-resident kcs (covers L2 latency of sb groups 0,1)
#pragma unroll
        for (int kc = 0; kc < RKC; ++kc) {
            short8 a = *(const short8*)&hrd[kc * 512];
#pragma unroll
            for (int i = 0; i < 4; ++i)
                acc[i] = __builtin_amdgcn_mfma_f32_16x16x32_bf16(a, bfr[kc][i], acc[i], 0, 0, 0);
        }

        // streamed groups 0,1: consume, then prefetch g+2 into freed buffer
#pragma unroll
        for (int g = 0; g < 2; ++g) {
            short8 a = *(const short8*)&hrd[(SKC0 + g) * 512];
#pragma unroll
            for (int i = 0; i < 4; ++i)
                acc[i] = __builtin_amdgcn_mfma_f32_16x16x32_bf16(a, sb[g][i], acc[i], 0, 0, 0);
            if (g + 2 < NS) {
#pragma unroll
                for (int i = 0; i < 4; ++i)
                    sb[g][i] = *(const short8*)(W1hp +
                        ((size_t)((4 * w + i) * 16 + SKC0 + g + 2) * 64 + lane) * 8);
            }
        }

        // LDS-resident kcs (covers L2 latency of sb groups 2,3)
#pragma unroll
        for (int j = 0; j < LKC; ++j) {
            short8 a = *(const short8*)&hrd[(RKC + j) * 512];
#pragma unroll
            for (int i = 0; i < 4; ++i) {
                short8 b = *(const short8*)&Wl[((size_t)(j * 32 + 4 * w + i) * 64 + lane) * 8];
                acc[i] = __builtin_amdgcn_mfma_f32_16x16x32_bf16(a, b, acc[i], 0, 0, 0);
            }
        }

        // remaining streamed groups
#pragma unroll
        for (int g = 2; g < NS; ++g) {
            short8 a = *(const short8*)&hrd[(SKC0 + g) * 512];
#pragma unroll
            for (int i = 0; i < 4; ++i)
                acc[i] = __builtin_amdgcn_mfma_f32_16x16x32_bf16(a, sb[g & 1][i], acc[i], 0, 0, 0);
            if (g + 2 < NS) {
#pragma unroll
                for (int i = 0; i < 4; ++i)
                    sb[g & 1][i] = *(const short8*)(W1hp +
                        ((size_t)((4 * w + i) * 16 + SKC0 + g + 2) * 64 + lane) * 8);
            }
        }

        // epilogue: h^{t+1} = tanh(acc + xpe[t]) -> other buffer
#pragma unroll
        for (int i = 0; i < 4; ++i) {
            Pack8 xh = (i < 2) ? x0 : x1;
#pragma unroll
            for (int r = 0; r < 4; ++r) {
                float v = acc[i][r] + bf2f(xh.h[(i & 1) * 4 + r]);
                Hb[widx[i] ^ (r << 3)] = f2bf(fast_tanh(v));
            }
            widx[i] ^= 8192;
        }
        roff ^= 8192;
        __syncthreads();
    }

    // ---- tail: out[:, 16w:16w+16) = h^512 @ W2 + b2 ----
    const float b2 = b2p[0];
    floatx4 acc = {0.f, 0.f, 0.f, 0.f};
#pragma unroll
    for (int kc = 0; kc < 16; ++kc) {
        short8 av = *(const short8*)&Hb[roff + kc * 512];
        Pack8 bv;
#pragma unroll
        for (int j = 0; j < 8; ++j)
            bv.h[j] = f2bf(W2[(size_t)(kc * 32 + q * 8 + j) * DOUT + w * 16 + m]);
        acc = __builtin_amdgcn_mfma_f32_16x16x32_bf16(av, bv.s, acc, 0, 0, 0);
    }
#pragma unroll
    for (int r = 0; r < 4; ++r)
        out[(size_t)(rg * 16 + q * 4 + r) * DOUT + w * 16 + m] = acc[r] + b2;
}

// ---------------------------------------------------------------------------
extern "C" void kernel_launch(void* const* d_in, const int* in_sizes, int n_in,
                              void* d_out, int out_size, void* d_ws, size_t ws_size,
                              hipStream_t stream) {
    const float* xs  = (const float*)d_in[0];
    const float* W1x = (const float*)d_in[1];
    const float* W1h = (const float*)d_in[2];
    const float* b1  = (const float*)d_in[3];
    const float* W2  = (const float*)d_in[4];
    const float* b2  = (const float*)d_in[5];
    float* out = (float*)d_out;

    // ws (bf16 elems): xpe | W1h packed | W1x packed
    unsigned short* xpe  = (unsigned short*)d_ws;
    unsigned short* w1hp = xpe + (size_t)T_STEPS * BATCH * DH;     // 67,108,864
    unsigned short* w1xp = w1hp + (size_t)DH * DH;                 // +262,144

    pack_b_kernel<<<(DH * DH + 255) / 256, 256, 0, stream>>>(W1h, w1hp, DH, DH);
    pack_b_kernel<<<(DIN * DH + 255) / 256, 256, 0, stream>>>(W1x, w1xp, DIN, DH);
    xproj_kernel<<<(T_STEPS * BATCH) / 16, 256, 0, stream>>>(xs, w1xp, b1, xpe);

    // LKC=2: Hb 32768 + Wl 65536 = 98304 B dynamic LDS (needs >64KB opt-in).
    // Fallback (opt-in unavailable): Hb only (32768 B), stream 6 kc from L2.
    // Decision is deterministic per machine -> graph-safe.
    constexpr size_t SMEM_BIG   = 32768 + 2 * 32768;   // 98304
    constexpr size_t SMEM_SMALL = 32768;
    hipError_t e = hipFuncSetAttribute(
        reinterpret_cast<const void*>(&rnn_kernel<2>),
        hipFuncAttributeMaxDynamicSharedMemorySize, (int)SMEM_BIG);
    if (e == hipSuccess) {
        rnn_kernel<2><<<RGRP, 512, SMEM_BIG, stream>>>(xpe, w1hp, W2, b2, out);
    } else {
        rnn_kernel<0><<<RGRP, 512, SMEM_SMALL, stream>>>(xpe, w1hp, W2, b2, out);
    }
}